// Round 5
// baseline (152.743 us; speedup 1.0000x reference)
//
#include <hip/hip_runtime.h>

typedef unsigned short u16;
typedef unsigned int   u32;
typedef __bf16 bf16x8 __attribute__((ext_vector_type(8)));
typedef __bf16 bf16x2 __attribute__((ext_vector_type(2)));
typedef float  f32x4  __attribute__((ext_vector_type(4)));

#define B_     2
#define N_     2048
#define DIM_   1024
#define HEADS_ 16
#define DH_    64
#define BH_    (B_*HEADS_)   // 32
#define ROWS_  (B_*N_)       // 4096

__device__ __forceinline__ u16 f2b(float f) {
  union { __bf16 h; u16 u; } v; v.h = (__bf16)f; return v.u;
}
__device__ __forceinline__ u32 pkb(float a, float b) {
  bf16x2 t; t[0] = (__bf16)a; t[1] = (__bf16)b;
  union { bf16x2 v; u32 u; } c; c.v = t; return c.u;
}
__device__ __forceinline__ float b2f(u16 h) {
  union { u32 u; float f; } v; v.u = ((u32)h) << 16;
  return v.f;
}
__device__ __forceinline__ void gload16(const void* g, void* l) {
  __builtin_amdgcn_global_load_lds(
      (const __attribute__((address_space(1))) void*)g,
      (__attribute__((address_space(3))) void*)l, 16, 0, 0);
}
__device__ __forceinline__ f32x4 mfma16(bf16x8 a, bf16x8 b, f32x4 c) {
  return __builtin_amdgcn_mfma_f32_16x16x32_bf16(a, b, c, 0, 0, 0);
}

// ---------------- RoPE tables: cos/sin (n, 32) ----------------
__global__ __launch_bounds__(256) void rope_tables(float* __restrict__ cosT,
                                                   float* __restrict__ sinT) {
  int tid = blockIdx.x * 256 + threadIdx.x;   // 65536 = 2048*32
  int n = tid >> 5, p = tid & 31;
  float freq = expf(-(2.0f * (float)p) * (9.210340371976184f / 64.0f));
  float ang = (float)n * freq;
  cosT[tid] = cosf(ang);
  sinT[tid] = sinf(ang);
}

// ---------------- LayerNorm -> bf16 ----------------
__global__ __launch_bounds__(256) void ln_kernel(const float* __restrict__ x,
    const float* __restrict__ lw, const float* __restrict__ lb,
    u16* __restrict__ xn) {
  int r = blockIdx.x, t = threadIdx.x;
  const float4* xr = (const float4*)(x + (size_t)r * DIM_);
  float4 v = xr[t];
  float s  = v.x + v.y + v.z + v.w;
  float s2 = v.x*v.x + v.y*v.y + v.z*v.z + v.w*v.w;
  #pragma unroll
  for (int off = 32; off >= 1; off >>= 1) {
    s  += __shfl_down(s, off);
    s2 += __shfl_down(s2, off);
  }
  __shared__ float ps[4], ps2[4], bc[2];
  int w = t >> 6, lane = t & 63;
  if (lane == 0) { ps[w] = s; ps2[w] = s2; }
  __syncthreads();
  if (t == 0) {
    float S = ps[0]+ps[1]+ps[2]+ps[3], S2 = ps2[0]+ps2[1]+ps2[2]+ps2[3];
    float mu = S * (1.0f/DIM_);
    float var = S2 * (1.0f/DIM_) - mu*mu;
    bc[0] = mu; bc[1] = rsqrtf(var + 1e-5f);
  }
  __syncthreads();
  float mu = bc[0], rs = bc[1];
  float4 wv = ((const float4*)lw)[t];
  float4 bv = ((const float4*)lb)[t];
  u32 lo = pkb((v.x-mu)*rs*wv.x + bv.x, (v.y-mu)*rs*wv.y + bv.y);
  u32 hi = pkb((v.z-mu)*rs*wv.z + bv.z, (v.w-mu)*rs*wv.w + bv.w);
  ((uint2*)xn)[(size_t)r*256 + t] = make_uint2(lo, hi);
}

// ---------------- f32 (R x C) -> bf16 transposed (C x R) ----------------
__global__ __launch_bounds__(256) void transpose_f32_bf16(const float* __restrict__ in,
    u16* __restrict__ out, int R, int C) {
  __shared__ float tile[32][33];
  int tx = threadIdx.x & 31, ty = threadIdx.x >> 5;
  int c0 = blockIdx.x * 32, r0 = blockIdx.y * 32;
  #pragma unroll
  for (int i = 0; i < 4; i++)
    tile[ty + i*8][tx] = in[(size_t)(r0 + ty + i*8) * C + c0 + tx];
  __syncthreads();
  #pragma unroll
  for (int i = 0; i < 4; i++)
    out[(size_t)(c0 + ty + i*8) * R + r0 + tx] = f2b(tile[tx][ty + i*8]);
}

// ---------------- GEMM: A (M x K bf16) x Bt (N x K bf16) ----------------
// 128x128 tile, BK=32, 3-buffer LDS, 2-deep prefetch, counted vmcnt (T3/T4).
// 1-D grid, XCD-swizzled: nb = (lin&7)*cpx + (lin>>3); bm = nb&31, bn = nb>>5.
// MODE 0: fused-RoPE scatter epilogue -> q (bh,n,d), k (bh,n,d), v^T (bh,d,n)
// MODE 1: out[r*N+c] = acc + bias[c]  (f32)
template<int MODE>
__global__ __launch_bounds__(256) void gemm_bt(
    const u16* __restrict__ A, const u16* __restrict__ Bt, int N, int K, int cpx,
    u16* __restrict__ qo, u16* __restrict__ ko, u16* __restrict__ vo,
    const float* __restrict__ cosT, const float* __restrict__ sinT,
    const float* __restrict__ bias, float* __restrict__ out) {
  __shared__ __align__(16) u16 lA[3][128*32];
  __shared__ __align__(16) u16 lB[3][128*32];
  int tid = threadIdx.x;
  int lane = tid & 63;
  int w = tid >> 6, wm = w >> 1, wn = w & 1;
  int l15 = lane & 15, g = lane >> 4;
  int lin = blockIdx.x;
  int nb = (lin & 7) * cpx + (lin >> 3);
  int bm = nb & 31, bn = nb >> 5;
  const f32x4 z = {0.f, 0.f, 0.f, 0.f};
  f32x4 acc[4][4];
  #pragma unroll
  for (int i = 0; i < 4; i++)
    #pragma unroll
    for (int j = 0; j < 4; j++)
      acc[i][j] = z;
  const u16* ag = A  + (size_t)(bm*128 + (tid>>2)) * K + (tid&3)*8;
  const u16* bg = Bt + (size_t)(bn*128 + (tid>>2)) * K + (tid&3)*8;
  int lo8 = tid*8;
  const int NK = K >> 5;

#define GSTAGE(k0, buf) { \
    gload16(ag + (k0),               &lA[buf][lo8]); \
    gload16(ag + (size_t)64*K + (k0), &lA[buf][lo8 + 2048]); \
    gload16(bg + (k0),               &lB[buf][lo8]); \
    gload16(bg + (size_t)64*K + (k0), &lB[buf][lo8 + 2048]); }

  GSTAGE(0, 0)
  GSTAGE(32, 1)
  asm volatile("s_waitcnt vmcnt(4)" ::: "memory");
  __builtin_amdgcn_s_barrier();

  int cur = 0, pfb = 2;
  #pragma unroll 1
  for (int t = 0; t < NK; ++t) {
    if (t + 2 < NK) GSTAGE((t + 2) << 5, pfb)
    bf16x8 af[4], bfr[4];
    #pragma unroll
    for (int mt = 0; mt < 4; mt++)
      af[mt] = *(const bf16x8*)(&lA[cur][(wm*64 + mt*16 + l15)*32 + g*8]);
    #pragma unroll
    for (int nt = 0; nt < 4; nt++)
      bfr[nt] = *(const bf16x8*)(&lB[cur][(wn*64 + nt*16 + l15)*32 + g*8]);
    __builtin_amdgcn_s_setprio(1);
    #pragma unroll
    for (int mt = 0; mt < 4; mt++)
      #pragma unroll
      for (int nt = 0; nt < 4; nt++)
        acc[mt][nt] = mfma16(af[mt], bfr[nt], acc[mt][nt]);
    __builtin_amdgcn_s_setprio(0);
    if (t + 1 < NK) {
      if (t + 2 < NK) { asm volatile("s_waitcnt vmcnt(4)" ::: "memory"); }
      else            { asm volatile("s_waitcnt vmcnt(0)" ::: "memory"); }
      __builtin_amdgcn_s_barrier();
    }
    cur = (cur + 1 == 3) ? 0 : cur + 1;
    pfb = (pfb + 1 == 3) ? 0 : pfb + 1;
  }
#undef GSTAGE

  const float qs = 0.125f * 1.4426950408889634f;  // DH^-1/2 * log2(e)
  #pragma unroll
  for (int mt = 0; mt < 4; mt++) {
    #pragma unroll
    for (int nt = 0; nt < 4; nt++) {
      #pragma unroll
      for (int reg = 0; reg < 4; reg++) {
        int rr = bm*128 + wm*64 + mt*16 + g*4 + reg;
        int cc = bn*128 + wn*64 + nt*16 + l15;
        float val = acc[mt][nt][reg];
        if (MODE == 0) {
          int which = cc >> 10, inner = cc & 1023;  // uniform per (nt)
          int h = inner >> 6, dd = inner & 63;
          int b = rr >> 11, np = rr & 2047;
          int bh = b*HEADS_ + h;
          if (which < 2) {
            // fused interleaved RoPE: partner = neighboring d (lane l15^1)
            float pv = __shfl_xor(val, 1);
            int p = dd >> 1;
            float c = cosT[np*32 + p];
            float s = sinT[np*32 + p];
            val = (dd & 1) ? (val*c + pv*s) : (val*c - pv*s);
            if (which == 0) val *= qs;
          }
          if (which == 0)      qo[((size_t)(bh*2048 + np))*64 + dd] = f2b(val);
          else if (which == 1) ko[((size_t)(bh*2048 + np))*64 + dd] = f2b(val);
          else                 vo[((size_t)(bh*64 + dd))*2048 + np] = f2b(val);
        } else {
          out[(size_t)rr * N + cc] = val + bias[cc];
        }
      }
    }
  }
}

// ---------------- Flash attention ----------------
// grid 512 (1-D, XCD-swizzled: each XCD owns 4 whole bh), 8 waves x 16 q-rows
// (QBLK=128), KBLK=64, log2-domain. 3-buffer LDS, 2-deep prefetch, counted
// vmcnt + raw barrier (T3/T4). Swapped QK^T; PV on V^T; O^T->O via LDS.
__global__ __launch_bounds__(512) void flash_attn(
    const u16* __restrict__ qbf, const u16* __restrict__ kbf,
    const u16* __restrict__ vt, u16* __restrict__ aout) {
  __shared__ __align__(16) char lK[3][8192];   // [key 64][128B], swizzled
  __shared__ __align__(16) char lV[3][8192];   // [d 64][128B], swizzled
  __shared__ __align__(16) char pl[8][2048];   // per-wave P / O-transpose buf
  int tid = threadIdx.x;
  int w = tid >> 6, lane = tid & 63;
  int l15 = lane & 15, g = lane >> 4;
  int lin = blockIdx.x;
  int nb = (lin & 7) * 64 + (lin >> 3);
  int bh = nb >> 4, qb = nb & 15;
  const f32x4 z = {0.f, 0.f, 0.f, 0.f};
  const u16* qbase = qbf + ((size_t)bh*2048 + qb*128 + w*16) * 64;
  bf16x8 qa0 = *(const bf16x8*)(qbase + l15*64 + g*8);
  bf16x8 qa1 = *(const bf16x8*)(qbase + l15*64 + 32 + g*8);
  const char* kb = (const char*)(kbf + (size_t)bh * 2048 * 64);
  const char* vb = (const char*)(vt  + (size_t)bh * 64 * 2048);
  // staging: 512 threads x 16B = one 8KB tile each for K and V per iter
  int srow = tid >> 3;                 // 0..63 (K: key row; V: d row)
  int sb   = (tid & 7) * 16;
  int soff = sb ^ ((srow & 7) << 4);   // inverse-swizzled source
  char* pw = pl[w];
  const int swz = (l15 & 7) << 4;      // row-XOR swizzle (K/V/P)

  float m = -1e30f, ls = 0.f;
  f32x4 o[4];
  #pragma unroll
  for (int i = 0; i < 4; i++) o[i] = z;

#define STAGE(t, buf) { \
    gload16(kb + (size_t)((t)*64 + srow) * 128 + soff, &lK[buf][(size_t)tid*16]); \
    gload16(vb + (size_t)srow * 4096 + (t)*128 + soff, &lV[buf][(size_t)tid*16]); }

  // prologue: fill buffers 0 and 1
  STAGE(0, 0)
  STAGE(1, 1)
  asm volatile("s_waitcnt vmcnt(2)" ::: "memory");
  __builtin_amdgcn_s_barrier();

  int cur = 0, pfb = 2;
  #pragma unroll 1
  for (int t = 0; t < 32; ++t) {
    if (t < 30) STAGE(t + 2, pfb)
    const char* Kc = lK[cur];
    const char* Vc = lV[cur];
    // QK^T (swapped): st[kt] holds S^T[key = kt*16+g*4+r][q = l15]
    f32x4 st[4];
    __builtin_amdgcn_s_setprio(1);
    #pragma unroll
    for (int kt = 0; kt < 4; kt++) {
      const char* krow = Kc + (kt*16 + l15) * 128;
      bf16x8 k0 = *(const bf16x8*)(krow + ((g*16) ^ swz));
      bf16x8 k1 = *(const bf16x8*)(krow + ((64 + g*16) ^ swz));
      f32x4 a = mfma16(k0, qa0, z);
      st[kt] = mfma16(k1, qa1, a);
    }
    __builtin_amdgcn_s_setprio(0);
    // online softmax (log2 domain): lane owns 16 keys of q-col l15
    float mt = fmaxf(fmaxf(st[0][0], st[0][1]), fmaxf(st[0][2], st[0][3]));
    #pragma unroll
    for (int kt = 1; kt < 4; kt++)
      mt = fmaxf(mt, fmaxf(fmaxf(st[kt][0], st[kt][1]),
                           fmaxf(st[kt][2], st[kt][3])));
    mt = fmaxf(mt, __shfl_xor(mt, 16));
    mt = fmaxf(mt, __shfl_xor(mt, 32));
    // defer-max: only rescale when tile max grew past threshold
    if (__any(mt > m + 8.0f)) {
      float mn = fmaxf(m, mt);
      float al = __builtin_amdgcn_exp2f(m - mn);
      m = mn;
      ls *= al;
      #pragma unroll
      for (int dt = 0; dt < 4; dt++)
        #pragma unroll
        for (int r = 0; r < 4; r++)
          o[dt][r] *= al;
    }
    float rs = 0.f;
    #pragma unroll
    for (int kt = 0; kt < 4; kt++)
      #pragma unroll
      for (int r = 0; r < 4; r++) {
        float p = __builtin_amdgcn_exp2f(st[kt][r] - m);
        st[kt][r] = p;
        rs += p;
      }
    rs += __shfl_xor(rs, 16);
    rs += __shfl_xor(rs, 32);
    ls += rs;
    // pack P -> wave-private LDS row q=l15, bytes = key*2 (swizzled)
    #pragma unroll
    for (int kt = 0; kt < 4; kt++) {
      u32 lo = pkb(st[kt][0], st[kt][1]);
      u32 hi = pkb(st[kt][2], st[kt][3]);
      *(uint2*)(pw + l15*128 + ((kt*32 + g*8) ^ swz)) = make_uint2(lo, hi);
    }
    // P^T B-frags: lane = (q=l15, keys g*8..+7) per 32-key chunk
    bf16x8 pb0 = *(const bf16x8*)(pw + l15*128 + ((g*16) ^ swz));
    bf16x8 pb1 = *(const bf16x8*)(pw + l15*128 + ((64 + g*16) ^ swz));
    // PV: O^T[d = dt*16+g*4+r][q = l15]
    __builtin_amdgcn_s_setprio(1);
    #pragma unroll
    for (int dt = 0; dt < 4; dt++) {
      const char* vrow = Vc + (dt*16 + l15) * 128;
      bf16x8 v0 = *(const bf16x8*)(vrow + ((g*16) ^ swz));
      bf16x8 v1 = *(const bf16x8*)(vrow + ((64 + g*16) ^ swz));
      o[dt] = mfma16(v0, pb0, o[dt]);
      o[dt] = mfma16(v1, pb1, o[dt]);
    }
    __builtin_amdgcn_s_setprio(0);
    if (t < 31) {
      if (t < 30) { asm volatile("s_waitcnt vmcnt(2)" ::: "memory"); }
      else        { asm volatile("s_waitcnt vmcnt(0)" ::: "memory"); }
      __builtin_amdgcn_s_barrier();
    }
    cur = (cur + 1 == 3) ? 0 : cur + 1;
    pfb = (pfb + 1 == 3) ? 0 : pfb + 1;
  }
#undef STAGE

  // epilogue: O^T -> O via wave-private LDS, coalesced 16B stores
  float rls = 1.0f / ls;
  #pragma unroll
  for (int dt = 0; dt < 4; dt++)
    #pragma unroll
    for (int r = 0; r < 4; r++) {
      int d = dt*16 + g*4 + r;
      *(u16*)(pw + l15*128 + ((d*2) ^ swz)) = f2b(o[dt][r] * rls);
    }
  int b = bh >> 4, h = bh & 15;
  int rl = lane >> 3;
  #pragma unroll
  for (int i = 0; i < 2; i++) {
    int row = i*8 + rl;          // local q row within the wave's 16
    uint4 ov = *(const uint4*)(pw + row*128 + (((lane & 7)*16) ^ (rl << 4)));
    int n = qb*128 + w*16 + row;
    *(uint4*)(aout + ((size_t)(b*2048 + n))*1024 + h*64 + (lane & 7)*8) = ov;
  }
}

extern "C" void kernel_launch(void* const* d_in, const int* in_sizes, int n_in,
                              void* d_out, int out_size, void* d_ws, size_t ws_size,
                              hipStream_t stream) {
  const float* x    = (const float*)d_in[0];
  const float* lw   = (const float*)d_in[1];
  const float* lb   = (const float*)d_in[2];
  const float* wqkv = (const float*)d_in[3];
  const float* wout = (const float*)d_in[4];
  const float* bout = (const float*)d_in[5];
  float* out = (float*)d_out;

  char* ws = (char*)d_ws;
  size_t off = 0;
  auto alloc = [&](size_t bytes) {
    char* p = ws + off;
    off += (bytes + 255) & ~(size_t)255;
    return p;
  };
  u16* xn   = (u16*)alloc((size_t)ROWS_*DIM_*2);
  u16* wqt  = (u16*)alloc((size_t)3072*1024*2);
  u16* wot  = (u16*)alloc((size_t)1024*1024*2);
  u16* qb   = (u16*)alloc((size_t)BH_*2048*64*2);
  u16* kb   = (u16*)alloc((size_t)BH_*2048*64*2);
  u16* vtb  = (u16*)alloc((size_t)BH_*2048*64*2);
  u16* aout = (u16*)alloc((size_t)ROWS_*1024*2);
  float* cosT = (float*)alloc((size_t)2048*32*4);
  float* sinT = (float*)alloc((size_t)2048*32*4);

  rope_tables<<<256, 256, 0, stream>>>(cosT, sinT);
  ln_kernel<<<ROWS_, 256, 0, stream>>>(x, lw, lb, xn);
  transpose_f32_bf16<<<dim3(96, 32), 256, 0, stream>>>(wqkv, wqt, 1024, 3072);
  transpose_f32_bf16<<<dim3(32, 32), 256, 0, stream>>>(wout, wot, 1024, 1024);
  gemm_bt<0><<<768, 256, 0, stream>>>(xn, wqt, 3072, 1024, 96,
                                      qb, kb, vtb, cosT, sinT, nullptr, nullptr);
  flash_attn<<<512, 512, 0, stream>>>(qb, kb, vtb, aout);
  gemm_bt<1><<<256, 256, 0, stream>>>(aout, wot, 1024, 1024, 32,
                                      nullptr, nullptr, nullptr, nullptr, nullptr,
                                      bout, out);
}